// Round 8
// baseline (66.838 us; speedup 1.0000x reference)
//
#include <hip/hip_runtime.h>

// Gaussian splat renderer: B=2, 9 params x 32x32 gaussians -> [B,3,128,128].
//
// r6 structure (fused, LDS table, 2 px/lane, 1 block/CU) with the inner loop
// forced to VOP3P packed-dual-f32 via inline asm. Evidence ledger:
//  - fixed harness floor F ~= 51us (poison fill 39.6 + resets); kernel K ~= 15us
//  - K fits a VALU/issue-bound model; LDS-BW model refuted (r6 halved LDS
//    bytes, saved only 1.9us)
//  - degenerate fits: "compiler scalarized v2f" (K~24 scalar, trans hidden)
//    vs "packed but trans serialized at issue" (K~15). This round forces
//    v_pk_fma_f32/v_pk_mul_f32/v_pk_add_f32 to discriminate:
//    scalarized -> K ~10us; already-packed -> unchanged => roofline.
//  - NOTE: v_pk_max_f32 does NOT exist on gfx950 (r7 compile fail); the
//    clamp uses __builtin_elementwise_max (2 scalar v_max_f32).
// Record stores NEGATED mu so dx = pk_add(px, nmux) needs no modifier.

#define NB   2
#define NG   1024            // gaussians per batch (32*32)
#define HOUT 128
#define WOUT 128
#define PSTRIDE 20           // floats per gaussian-PAIR record (18 used + pad)
#define NCHUNK 16

typedef float v2f __attribute__((ext_vector_type(2)));

__device__ __forceinline__ float fast_exp(float x) {
    return __builtin_amdgcn_exp2f(x * 1.4426950408889634f);
}
__device__ __forceinline__ float fast_sigmoid(float x) {
    float e = __builtin_amdgcn_exp2f(-x * 1.4426950408889634f);
    return __builtin_amdgcn_rcpf(1.0f + e);
}
__device__ __forceinline__ float fast_tanh(float x) {
    float e = __builtin_amdgcn_exp2f(-x * 2.8853900817779268f);
    return fmaf(2.0f, __builtin_amdgcn_rcpf(1.0f + e), -1.0f);
}

// Forced VOP3P packed dual-f32 ops (64-bit VGPR-pair operands).
__device__ __forceinline__ v2f pk_add(v2f a, v2f b) {
    v2f d;
    asm("v_pk_add_f32 %0, %1, %2" : "=v"(d) : "v"(a), "v"(b));
    return d;
}
__device__ __forceinline__ v2f pk_mul(v2f a, v2f b) {
    v2f d;
    asm("v_pk_mul_f32 %0, %1, %2" : "=v"(d) : "v"(a), "v"(b));
    return d;
}
__device__ __forceinline__ v2f pk_fma(v2f a, v2f b, v2f c) {
    v2f d;
    asm("v_pk_fma_f32 %0, %1, %2, %3" : "=v"(d) : "v"(a), "v"(b), "v"(c));
    return d;
}

__global__ __launch_bounds__(1024) void gauss_fused(const float* __restrict__ params,
                                                    float* __restrict__ out) {
    __shared__ __align__(16) float gtab[(NG / 2) * PSTRIDE];  // 40 KB
    __shared__ float4 sred[NCHUNK][128];                      // 32 KB partials

    const int tx  = threadIdx.x;             // pixel lane   [0,64)
    const int ty  = threadIdx.y;             // chunk        [0,16)
    const int tid = ty * 64 + tx;
    const int blk = blockIdx.x;
    const int b   = blk >> 7;                // 128 blocks (rows) per batch
    const int row = blk & 127;               // image row
    const int pixb = row << 7;               // first pixel of this row

    // ---------------- per-gaussian setup: thread tid -> gaussian tid -------
    {
        const int n = tid;
        const int gh = n >> 5;
        const int gw = n & 31;

        const float* P = params + b * 9 * NG + n;   // channel stride = 1024
        float p0 = P[0 * NG];
        float p1 = P[1 * NG];
        float p2 = P[2 * NG];
        float p3 = P[3 * NG];
        float p4 = P[4 * NG];
        float p5 = P[5 * NG];
        float p6 = P[6 * NG];
        float p7 = P[7 * NG];
        float p8 = P[8 * NG];

        // base_grid: linspace(-31/32, 31/32, 32) -> -0.96875 + i/16; off 2/32
        float mux = -0.96875f + (float)gw * 0.0625f + fast_tanh(p0) * 0.0625f;
        float muy = -0.96875f + (float)gh * 0.0625f + fast_tanh(p1) * 0.0625f;

        // cov = L L^T + 1e-5 I,  L = [[e^a,0],[b,e^c]]
        float ea  = fast_exp(p2);
        float ec  = fast_exp(p4);
        float c00 = ea * ea + 1e-5f;
        float c01 = p3 * ea;
        float c11 = p3 * p3 + ec * ec + 1e-5f;
        float det = c00 * c11 - c01 * c01;
        float id  = 1.0f / det;            // exact divide: det can be ~1e-10
        float Sa  =  c11 * id;
        float Sb  = -c01 * id;
        float Sc  =  c00 * id;

        // fold -0.5*log2(e) so the render loop computes exp2 directly
        const float s = -0.72134752044448169f;   // -0.5 * log2(e)
        float A  = s * Sa;
        float B2 = 2.0f * s * Sb;
        float C  = s * Sc;

        float cr = fast_sigmoid(p5);
        float cg = fast_sigmoid(p6);
        float cb = fast_sigmoid(p7);
        float op = fast_sigmoid(p8);

        // pair-blocked layout: record (n>>1), half (n&1); field stride 2.
        // mu stored NEGATED so the loop uses pk_add for dx/dy.
        float* o = gtab + (n >> 1) * PSTRIDE + (n & 1);
        o[0]  = -mux; o[2]  = -muy; o[4]  = A;       o[6]  = B2;
        o[8]  = C;    o[10] = op;   o[12] = op * cr; o[14] = op * cg;
        o[16] = op * cb;
    }
    __syncthreads();

    // ---------------- render: 2 pixels per lane, same row ------------------
    const float py  = -1.0f + (float)row * (2.0f / 127.0f);
    const float pxA = -1.0f + (float)tx * (2.0f / 127.0f);
    const float pxB = -1.0f + (float)(tx + 64) * (2.0f / 127.0f);
    const v2f py2  = {py, py};
    const v2f pxA2 = {pxA, pxA};
    const v2f pxB2 = {pxB, pxB};
    const v2f clampv = {-28.853900817779268f, -28.853900817779268f};

    // wave-uniform chunk base; uniform-address LDS reads broadcast.
    const v2f* __restrict__ gp =
        (const v2f*)(gtab + ty * (NG / 2 / NCHUNK) * PSTRIDE);

    v2f wsA = {0,0}, arA = {0,0}, agA = {0,0}, abA = {0,0};
    v2f wsB = {0,0}, arB = {0,0}, agB = {0,0}, abB = {0,0};

    #pragma unroll 4
    for (int j = 0; j < NG / 2 / NCHUNK; ++j) {     // 32 pair-iterations
        const v2f* __restrict__ r = gp + j * (PSTRIDE / 2);
        v2f nmux2 = r[0], nmuy2 = r[1];
        v2f A2    = r[2], B22   = r[3], C2 = r[4];
        v2f op2   = r[5], ocr2  = r[6], ocg2 = r[7], ocb2 = r[8];

        // shared across the two pixels (same row => same dy)
        v2f dy   = pk_add(py2, nmuy2);
        v2f bdy  = pk_mul(B22, dy);
        v2f t    = pk_mul(C2, dy);
        v2f cdy2 = pk_mul(t, dy);

        // pixel A
        v2f dxA = pk_add(pxA2, nmux2);
        v2f eA  = pk_fma(dxA, pk_fma(A2, dxA, bdy), cdy2);
        eA = __builtin_elementwise_max(eA, clampv);   // no v_pk_max on gfx950
        v2f kA = {__builtin_amdgcn_exp2f(eA.x), __builtin_amdgcn_exp2f(eA.y)};
        wsA = pk_fma(op2,  kA, wsA);
        arA = pk_fma(ocr2, kA, arA);
        agA = pk_fma(ocg2, kA, agA);
        abA = pk_fma(ocb2, kA, abA);

        // pixel B
        v2f dxB = pk_add(pxB2, nmux2);
        v2f eB  = pk_fma(dxB, pk_fma(A2, dxB, bdy), cdy2);
        eB = __builtin_elementwise_max(eB, clampv);
        v2f kB = {__builtin_amdgcn_exp2f(eB.x), __builtin_amdgcn_exp2f(eB.y)};
        wsB = pk_fma(op2,  kB, wsB);
        arB = pk_fma(ocr2, kB, arB);
        agB = pk_fma(ocg2, kB, agB);
        abB = pk_fma(ocb2, kB, abB);
    }

    sred[ty][tx]      = make_float4(wsA.x + wsA.y, arA.x + arA.y,
                                    agA.x + agA.y, abA.x + abA.y);
    sred[ty][tx + 64] = make_float4(wsB.x + wsB.y, arB.x + arB.y,
                                    agB.x + agB.y, abB.x + abB.y);
    __syncthreads();

    // ---------------- combine chunks, normalize, store (128 px/block) ------
    if (tid < 128) {
        float4 a = sred[0][tid];
        #pragma unroll
        for (int c = 1; c < NCHUNK; ++c) {
            float4 t4 = sred[c][tid];
            a.x += t4.x; a.y += t4.y; a.z += t4.z; a.w += t4.w;
        }
        float inv = 1.0f / (a.x + 1e-8f);
        float* ob = out + b * 3 * (HOUT * WOUT) + pixb + tid;
        ob[0]               = a.y * inv;
        ob[HOUT * WOUT]     = a.z * inv;
        ob[2 * HOUT * WOUT] = a.w * inv;
    }
}

extern "C" void kernel_launch(void* const* d_in, const int* in_sizes, int n_in,
                              void* d_out, int out_size, void* d_ws, size_t ws_size,
                              hipStream_t stream) {
    const float* params = (const float*)d_in[0];
    float* out = (float*)d_out;
    (void)d_ws; (void)ws_size;   // workspace intentionally unused

    // 2 batches * 128 rows = 256 blocks (1 per CU), 1024 threads each
    hipLaunchKernelGGL(gauss_fused, dim3(NB * 128), dim3(64, NCHUNK), 0, stream,
                       params, out);
}